// Round 4
// baseline (165.874 us; speedup 1.0000x reference)
//
#include <hip/hip_runtime.h>
#include <math.h>

// Causal flash attention, B=2 H=16 S=2048 D=64, fp32 in/out, bf16 MFMA compute.
// R9: ZERO-SYNC fattn. No LDS, no barriers, no staging: K/V fragments read
// directly from L2 (K/V per bh = 512 KB << 4 MB XCD L2; guide m169: don't
// stage what the cache serves). Each wave owns one 32-row q-set, loops its
// 32-key units with kf prefetched 1 unit ahead and vf issued before QK (QK
// MFMA + exp2 hides vf latency). l via ones-MFMA (VALU is the critical pipe
// now; offload the row-sum to the idle MFMA pipe). Wave-local epilogue writes
// final fp32 O directly: no combine kernel, no partial buffers.
// Balance: block (bh,j) = 4 waves with q-sets {j,31-j,32+j,63-j} -> every
// block exactly 130 units; wave->size order alternated by (bh+j)&1.
// Carried: Q pre-scaled bf16 prepass, P pack via v_perm, permlane32_swap
// P-exchange, persistent zero-C, setprio(1) on MFMA clusters.

constexpr int kS   = 2048;
constexpr int kD   = 64;
constexpr int kBH  = 32;
constexpr int kPadP = 72;   // prep-kernel LDS pad only

typedef short short8 __attribute__((ext_vector_type(8)));
typedef float float4v __attribute__((ext_vector_type(4)));
typedef float float16v __attribute__((ext_vector_type(16)));
typedef unsigned int u32;
typedef unsigned short u16;

static __device__ inline u16 f2bf(float f) {
  union { float f; unsigned u; } v; v.f = f;
  unsigned r = v.u + 0x7FFF + ((v.u >> 16) & 1);   // RNE
  return (u16)(r >> 16);
}

static __device__ inline short8 pack8(float4v a, float4v b) {
  short8 r;
  r[0] = (short)f2bf(a[0]); r[1] = (short)f2bf(a[1]);
  r[2] = (short)f2bf(a[2]); r[3] = (short)f2bf(a[3]);
  r[4] = (short)f2bf(b[0]); r[5] = (short)f2bf(b[1]);
  r[6] = (short)f2bf(b[2]); r[7] = (short)f2bf(b[3]);
  return r;
}

// half-swap: v_permlane32_swap_b32 A, B : A.hi-lanes <-> B.lo-lanes
static __device__ inline void swap32(u32 a, u32 b, u32& oa, u32& ob) {
#if __has_builtin(__builtin_amdgcn_permlane32_swap)
  auto r = __builtin_amdgcn_permlane32_swap(a, b, false, false);
  oa = r[0]; ob = r[1];
#else
  asm volatile("v_permlane32_swap_b32 %0, %1" : "+v"(a), "+v"(b));
  oa = a; ob = b;
#endif
}

// ---- prepass: Q -> scaled bf16 [bh][s][d]; K -> bf16 [bh][s][d];
//               V -> bf16 transposed [bh][d][s] ----
__global__ __launch_bounds__(256)
void prep_kernel(const float* __restrict__ Q, const float* __restrict__ K,
                 const float* __restrict__ V,
                 u16* __restrict__ Qb, u16* __restrict__ Kb, u16* __restrict__ VT) {
  __shared__ u16 tile[64 * kPadP];
  const int tid = threadIdx.x;
  const int bh = blockIdx.y, st = blockIdx.x;
  const size_t ibase = (size_t)bh * kS * kD + (size_t)st * 64 * kD;
  const int r  = tid >> 2;
  const int c0 = (tid & 3) * 16;
  {
    const float scl = 0.125f * 1.44269504089f;   // 1/sqrt(64) * log2(e)
    const float* qp = Q + ibase + (size_t)r * kD + c0;
    float4v a = *(const float4v*)(qp);
    float4v b = *(const float4v*)(qp + 4);
    float4v c = *(const float4v*)(qp + 8);
    float4v d = *(const float4v*)(qp + 12);
    #pragma unroll
    for (int i = 0; i < 4; ++i) { a[i] *= scl; b[i] *= scl; c[i] *= scl; d[i] *= scl; }
    u16* dst = Qb + ibase + (size_t)r * kD + c0;
    *(short8*)dst       = pack8(a, b);
    *(short8*)(dst + 8) = pack8(c, d);
  }
  {
    const float* kp = K + ibase + (size_t)r * kD + c0;
    float4v a = *(const float4v*)(kp);
    float4v b = *(const float4v*)(kp + 4);
    float4v c = *(const float4v*)(kp + 8);
    float4v d = *(const float4v*)(kp + 12);
    u16* dst = Kb + ibase + (size_t)r * kD + c0;
    *(short8*)dst       = pack8(a, b);
    *(short8*)(dst + 8) = pack8(c, d);
  }
  {
    const float* vp = V + ibase + (size_t)r * kD + c0;
    float4v a = *(const float4v*)(vp);
    float4v b = *(const float4v*)(vp + 4);
    float4v c = *(const float4v*)(vp + 8);
    float4v d = *(const float4v*)(vp + 12);
    u16* t = &tile[r * kPadP + c0];
    *(short8*)t       = pack8(a, b);
    *(short8*)(t + 8) = pack8(c, d);
  }
  __syncthreads();
  {
    const int dd = tid >> 2;
    const int s0 = (tid & 3) * 16;
    short8 w0, w1;
    #pragma unroll
    for (int i = 0; i < 8; ++i) {
      w0[i] = (short)tile[(s0 + i) * kPadP + dd];
      w1[i] = (short)tile[(s0 + 8 + i) * kPadP + dd];
    }
    u16* vdst = VT + (size_t)bh * kD * kS + (size_t)dd * kS + st * 64 + s0;
    *(short8*)vdst       = w0;
    *(short8*)(vdst + 8) = w1;
  }
}

// ---- main flash kernel: zero-sync, direct-from-L2 fragments, final O ----
__global__ __launch_bounds__(256, 2)
void fattn_kernel(const u16* __restrict__ Qb, const u16* __restrict__ Kb,
                  const u16* __restrict__ VT, float* __restrict__ O) {
  const int tid  = threadIdx.x;
  const int wave = tid >> 6;
  const int lane = tid & 63;
  const int l31  = lane & 31;
  const int h    = lane >> 5;

  const int bh = blockIdx.y;
  const int j  = blockIdx.x;   // 0..15

  // q-set selection: block covers {j, 31-j, 32+j, 63-j} (130 units total);
  // wave->size order alternated by (bh+j)&1 to spread SIMD load.
  const int we = ((bh + j) & 1) ? (3 - wave) : wave;
  const int s  = (we & 2) ? ((we & 1) ? 63 - j : 32 + j)
                          : ((we & 1) ? 31 - j : j);
  const int q0 = s * 32;

  const size_t base  = (size_t)bh * kS * kD;
  const size_t vbase = (size_t)bh * kD * kS;

  float16v zf;
  #pragma unroll
  for (int i = 0; i < 16; ++i) zf[i] = 0.f;

  short8 ones;
  #pragma unroll
  for (int i = 0; i < 8; ++i) ones[i] = (short)0x3F80;

  // Q fragments (pre-scaled bf16): lane covers q = q0 + l31, k-half h
  short8 qf[4];
  {
    const u16* qp = Qb + base + (size_t)(q0 + l31) * kD + h * 8;
    #pragma unroll
    for (int dk = 0; dk < 4; ++dk) qf[dk] = *(const short8*)(qp + dk * 16);
  }

  // fragment base pointers
  const u16* kptr = Kb + base + (size_t)l31 * kD + h * 8;       // + k*2048 + dk*16
  const u16* vp0  = VT + vbase + (size_t)l31 * kS + h * 8;      // + k*32 + c*16
  const u16* vp1  = vp0 + (size_t)32 * kS;

  float16v acc0 = zf, acc1 = zf, lacc = zf;

  short8 kfA[4], kfB[4];
  // preload kf for k=0
  #pragma unroll
  for (int dk = 0; dk < 4; ++dk) kfA[dk] = *(const short8*)(kptr + dk * 16);

  const int qg = q0 + l31;   // this lane's q column (for diag mask)

  auto step = [&](short8* kfc, short8* kfn, int k) {
    // issue vf loads for current unit (latency hidden by QK MFMAs + exp2)
    const u16* vk0 = vp0 + k * 32;
    const u16* vk1 = vp1 + k * 32;
    const short8 vf0 = *(const short8*)(vk0);
    const short8 vf1 = *(const short8*)(vk1);
    const short8 vf2 = *(const short8*)(vk0 + 16);
    const short8 vf3 = *(const short8*)(vk1 + 16);
    // prefetch kf for next unit (clamped: redundant reload on last iter)
    {
      const int kn = (k < s) ? (k + 1) : k;
      const u16* kp = kptr + (size_t)kn * 2048;
      #pragma unroll
      for (int dk = 0; dk < 4; ++dk) kfn[dk] = *(const short8*)(kp + dk * 16);
    }

    // S^T = K * Q^T (rows = keys, cols = q)
    __builtin_amdgcn_s_setprio(1);
    float16v sv = __builtin_amdgcn_mfma_f32_32x32x16_bf16(kfc[0], qf[0], zf, 0, 0, 0);
    sv = __builtin_amdgcn_mfma_f32_32x32x16_bf16(kfc[1], qf[1], sv, 0, 0, 0);
    sv = __builtin_amdgcn_mfma_f32_32x32x16_bf16(kfc[2], qf[2], sv, 0, 0, 0);
    sv = __builtin_amdgcn_mfma_f32_32x32x16_bf16(kfc[3], qf[3], sv, 0, 0, 0);
    __builtin_amdgcn_s_setprio(0);

    if (k == s) {   // diagonal subtile
      #pragma unroll
      for (int r = 0; r < 16; ++r) {
        const int kg = k * 32 + (r & 3) + 8 * (r >> 2) + 4 * h;
        if (kg > qg) sv[r] = -1e30f;
      }
    }

    // p = exp2(s), pack (truncate) via v_perm
    u32 pk[8];
    #pragma unroll
    for (int g2 = 0; g2 < 4; ++g2) {
      const u32 u0 = __float_as_uint(__builtin_amdgcn_exp2f(sv[4 * g2 + 0]));
      const u32 u1 = __float_as_uint(__builtin_amdgcn_exp2f(sv[4 * g2 + 1]));
      const u32 u2 = __float_as_uint(__builtin_amdgcn_exp2f(sv[4 * g2 + 2]));
      const u32 u3 = __float_as_uint(__builtin_amdgcn_exp2f(sv[4 * g2 + 3]));
      pk[2 * g2]     = __builtin_amdgcn_perm(u1, u0, 0x07060302u);
      pk[2 * g2 + 1] = __builtin_amdgcn_perm(u3, u2, 0x07060302u);
    }

    // exchange partner half via permlane32_swap; PV + ones-MFMA for l
    {
      union { u32 u[4]; short8 s8; } pf;
      swap32(pk[0], pk[2], pf.u[0], pf.u[2]);
      swap32(pk[1], pk[3], pf.u[1], pf.u[3]);
      __builtin_amdgcn_s_setprio(1);
      acc0 = __builtin_amdgcn_mfma_f32_32x32x16_bf16(pf.s8, vf0, acc0, 0, 0, 0);
      acc1 = __builtin_amdgcn_mfma_f32_32x32x16_bf16(pf.s8, vf1, acc1, 0, 0, 0);
      lacc = __builtin_amdgcn_mfma_f32_32x32x16_bf16(pf.s8, ones, lacc, 0, 0, 0);
      __builtin_amdgcn_s_setprio(0);
    }
    {
      union { u32 u[4]; short8 s8; } pf;
      swap32(pk[4], pk[6], pf.u[0], pf.u[2]);
      swap32(pk[5], pk[7], pf.u[1], pf.u[3]);
      __builtin_amdgcn_s_setprio(1);
      acc0 = __builtin_amdgcn_mfma_f32_32x32x16_bf16(pf.s8, vf2, acc0, 0, 0, 0);
      acc1 = __builtin_amdgcn_mfma_f32_32x32x16_bf16(pf.s8, vf3, acc1, 0, 0, 0);
      lacc = __builtin_amdgcn_mfma_f32_32x32x16_bf16(pf.s8, ones, lacc, 0, 0, 0);
      __builtin_amdgcn_s_setprio(0);
    }
  };

  int k = 0;
  while (true) {
    step(kfA, kfB, k); if (++k > s) break;
    step(kfB, kfA, k); if (++k > s) break;
  }

  // ---- wave-local epilogue: O = acc / l, final fp32 ----
  #pragma unroll
  for (int r = 0; r < 16; ++r) {
    const int row = (r & 3) + 8 * (r >> 2) + 4 * h;
    const float inv = 1.f / lacc[r];
    float* op = O + ((size_t)bh * kS + q0 + row) * kD;
    op[l31]      = acc0[r] * inv;
    op[l31 + 32] = acc1[r] * inv;
  }
}

extern "C" void kernel_launch(void* const* d_in, const int* in_sizes, int n_in,
                              void* d_out, int out_size, void* d_ws, size_t ws_size,
                              hipStream_t stream) {
  const float* Q = (const float*)d_in[0];
  const float* K = (const float*)d_in[1];
  const float* V = (const float*)d_in[2];
  float* O = (float*)d_out;

  const size_t nKV = (size_t)kBH * kS * kD;      // 4.19M elems
  u16* Qb = (u16*)d_ws;                          // 8.39 MB
  u16* Kb = Qb + nKV;                            // 8.39 MB
  u16* VT = Kb + nKV;                            // 8.39 MB

  dim3 gprep(kS / 64, kBH);
  prep_kernel<<<gprep, 256, 0, stream>>>(Q, K, V, Qb, Kb, VT);
  dim3 grid(16, kBH);   // x: j (4 q-sets per block), y: bh
  fattn_kernel<<<grid, 256, 0, stream>>>(Qb, Kb, VT, O);
}

// Round 5
// 142.915 us; speedup vs baseline: 1.1606x; 1.1606x over previous
//
#include <hip/hip_runtime.h>
#include <math.h>

// Causal flash attention, B=2 H=16 S=2048 D=64, fp32 in/out, bf16 MFMA compute.
// R10: zero-sync fattn with COALESCED fragment buffers. Prepass writes Q/K/V
// in MFMA fragment order frag[bh][unit][chunk][lane] so every fattn load is a
// coalesced global_load_dwordx4 (lane*16B) from L2. No LDS, no barriers.
// 2048 single-wave blocks (one 32-q-row set each), XCD-chunked (2 bh = 2MB
// frag working set per XCD L2) + LPT order (largest s first, dynamic backfill
// balances). Register double-buffer prefetch one unit deep. l via ones-MFMA
// (VALU is the tighter pipe). Wave-local epilogue writes final fp32 O.
// Carried: Q pre-scaled bf16 prepass, P pack via v_perm, permlane32_swap
// P-exchange, persistent zero-C, setprio(1) on MFMA clusters.

constexpr int kS   = 2048;
constexpr int kD   = 64;
constexpr int kBH  = 32;
constexpr int kPadP = 72;           // prep-kernel LDS pad only
constexpr int kFragBH = 64 * 4 * 512;   // u16 per bh: 64 units x 4 chunks x 512

typedef short short8 __attribute__((ext_vector_type(8)));
typedef float float4v __attribute__((ext_vector_type(4)));
typedef float float16v __attribute__((ext_vector_type(16)));
typedef unsigned int u32;
typedef unsigned short u16;

static __device__ inline u16 f2bf(float f) {
  union { float f; unsigned u; } v; v.f = f;
  unsigned r = v.u + 0x7FFF + ((v.u >> 16) & 1);   // RNE
  return (u16)(r >> 16);
}

static __device__ inline short8 pack8(float4v a, float4v b) {
  short8 r;
  r[0] = (short)f2bf(a[0]); r[1] = (short)f2bf(a[1]);
  r[2] = (short)f2bf(a[2]); r[3] = (short)f2bf(a[3]);
  r[4] = (short)f2bf(b[0]); r[5] = (short)f2bf(b[1]);
  r[6] = (short)f2bf(b[2]); r[7] = (short)f2bf(b[3]);
  return r;
}

// half-swap: v_permlane32_swap_b32 A, B : A.hi-lanes <-> B.lo-lanes
static __device__ inline void swap32(u32 a, u32 b, u32& oa, u32& ob) {
#if __has_builtin(__builtin_amdgcn_permlane32_swap)
  auto r = __builtin_amdgcn_permlane32_swap(a, b, false, false);
  oa = r[0]; ob = r[1];
#else
  asm volatile("v_permlane32_swap_b32 %0, %1" : "+v"(a), "+v"(b));
  oa = a; ob = b;
#endif
}

// ---- prepass: write fragment-order buffers ----
// Qf/Kf chunk(set/unit u, dk, lane): elem = X[row u*32 + (lane&31)][dk*16 + (lane>>5)*8 .. +8]
// Vf  chunk(unit u, c, lane): elem = V^T[d = (c&1)*32 + (lane&31)][key u*32 + (c>>1)*16 + (lane>>5)*8 .. +8]
__global__ __launch_bounds__(256)
void prep_kernel(const float* __restrict__ Q, const float* __restrict__ K,
                 const float* __restrict__ V,
                 u16* __restrict__ Qf, u16* __restrict__ Kf, u16* __restrict__ Vf) {
  __shared__ u16 tile[64 * kPadP];
  const int tid = threadIdx.x;
  const int bh = blockIdx.y, st = blockIdx.x;
  const size_t ibase = (size_t)bh * kS * kD + (size_t)st * 64 * kD;
  const size_t fbase = (size_t)bh * kFragBH;
  const int r  = tid >> 2;        // row within 64-row tile
  const int c0 = (tid & 3) * 16;  // col start
  const int dk = tid & 3;
  const int U  = st * 2 + (r >> 5);   // global 32-row unit/set index
  const int lr = r & 31;
  {
    const float scl = 0.125f * 1.44269504089f;   // 1/sqrt(64) * log2(e)
    const float* qp = Q + ibase + (size_t)r * kD + c0;
    float4v a = *(const float4v*)(qp);
    float4v b = *(const float4v*)(qp + 4);
    float4v c = *(const float4v*)(qp + 8);
    float4v d = *(const float4v*)(qp + 12);
    #pragma unroll
    for (int i = 0; i < 4; ++i) { a[i] *= scl; b[i] *= scl; c[i] *= scl; d[i] *= scl; }
    u16* dst = Qf + fbase + (size_t)(U * 4 + dk) * 512;
    *(short8*)(dst + lr * 8)        = pack8(a, b);   // h=0 chunk (d c0..c0+7)
    *(short8*)(dst + (32 + lr) * 8) = pack8(c, d);   // h=1 chunk (d c0+8..c0+15)
  }
  {
    const float* kp = K + ibase + (size_t)r * kD + c0;
    float4v a = *(const float4v*)(kp);
    float4v b = *(const float4v*)(kp + 4);
    float4v c = *(const float4v*)(kp + 8);
    float4v d = *(const float4v*)(kp + 12);
    u16* dst = Kf + fbase + (size_t)(U * 4 + dk) * 512;
    *(short8*)(dst + lr * 8)        = pack8(a, b);
    *(short8*)(dst + (32 + lr) * 8) = pack8(c, d);
  }
  {
    const float* vp = V + ibase + (size_t)r * kD + c0;
    float4v a = *(const float4v*)(vp);
    float4v b = *(const float4v*)(vp + 4);
    float4v c = *(const float4v*)(vp + 8);
    float4v d = *(const float4v*)(vp + 12);
    u16* t = &tile[r * kPadP + c0];
    *(short8*)t       = pack8(a, b);
    *(short8*)(t + 8) = pack8(c, d);
  }
  __syncthreads();
  {
    const int dd = tid >> 2;          // d-row of V^T
    const int s0 = (tid & 3) * 16;    // key col start within tile
    short8 w0, w1;
    #pragma unroll
    for (int i = 0; i < 8; ++i) {
      w0[i] = (short)tile[(s0 + i) * kPadP + dd];
      w1[i] = (short)tile[(s0 + 8 + i) * kPadP + dd];
    }
    const int ku   = st * 2 + (s0 >> 5);        // unit index
    const int koff = s0 & 31;                   // 0 or 16
    const int c    = ((koff >> 4) << 1) | (dd >> 5);
    u16* vdst = Vf + fbase + (size_t)(ku * 4 + c) * 512;
    *(short8*)(vdst + (dd & 31) * 8)        = w0;   // h=0 (key +0..7)
    *(short8*)(vdst + (32 + (dd & 31)) * 8) = w1;   // h=1 (key +8..15)
  }
}

// ---- main flash kernel: zero-sync, coalesced frag loads, final O ----
__global__ __launch_bounds__(64, 2)
void fattn_kernel(const u16* __restrict__ Qf, const u16* __restrict__ Kf,
                  const u16* __restrict__ Vf, float* __restrict__ O) {
  const int lane = threadIdx.x;
  const int l31  = lane & 31;
  const int h    = lane >> 5;

  // XCD-chunked (8 chunks of 256 blocks = 2 bh each) + LPT (largest s first)
  const int orig = ((blockIdx.x & 7) << 8) | (blockIdx.x >> 3);
  const int pr   = orig >> 7;          // bh pair 0..15
  const int r2   = orig & 127;
  const int s    = 63 - (r2 >> 1);     // q-set index, biggest first
  const int bh   = pr * 2 + (r2 & 1);
  const int q0   = s * 32;

  const size_t fb = (size_t)bh * kFragBH;
  const u16* kp = Kf + fb + lane * 8;   // + u*2048 + dk*512
  const u16* vp = Vf + fb + lane * 8;   // + u*2048 + c*512

  float16v zf;
  #pragma unroll
  for (int i = 0; i < 16; ++i) zf[i] = 0.f;

  short8 ones;
  #pragma unroll
  for (int i = 0; i < 8; ++i) ones[i] = (short)0x3F80;

  // Q fragments (pre-scaled bf16), coalesced
  short8 qf[4];
  {
    const u16* qp = Qf + fb + (size_t)(s * 4) * 512 + lane * 8;
    #pragma unroll
    for (int dk = 0; dk < 4; ++dk) qf[dk] = *(const short8*)(qp + dk * 512);
  }

  float16v acc0 = zf, acc1 = zf, lacc = zf;
  const int qg = q0 + l31;   // this lane's q column (diag mask)

  short8 kA[4], vA[4], kB[4], vB[4];
  #pragma unroll
  for (int dk = 0; dk < 4; ++dk) kA[dk] = *(const short8*)(kp + dk * 512);
  #pragma unroll
  for (int c = 0; c < 4; ++c)    vA[c]  = *(const short8*)(vp + c * 512);

  auto step = [&](const short8* kc, const short8* vc, short8* kn, short8* vn, int k) {
    // prefetch next unit (clamped redundant reload on last iter)
    const int knext = (k < s) ? (k + 1) : k;
    #pragma unroll
    for (int dk = 0; dk < 4; ++dk) kn[dk] = *(const short8*)(kp + knext * 2048 + dk * 512);
    #pragma unroll
    for (int c = 0; c < 4; ++c)    vn[c]  = *(const short8*)(vp + knext * 2048 + c * 512);

    // S^T = K * Q^T (rows = keys, cols = q)
    __builtin_amdgcn_s_setprio(1);
    float16v sv = __builtin_amdgcn_mfma_f32_32x32x16_bf16(kc[0], qf[0], zf, 0, 0, 0);
    sv = __builtin_amdgcn_mfma_f32_32x32x16_bf16(kc[1], qf[1], sv, 0, 0, 0);
    sv = __builtin_amdgcn_mfma_f32_32x32x16_bf16(kc[2], qf[2], sv, 0, 0, 0);
    sv = __builtin_amdgcn_mfma_f32_32x32x16_bf16(kc[3], qf[3], sv, 0, 0, 0);
    __builtin_amdgcn_s_setprio(0);

    if (k == s) {   // diagonal subtile
      #pragma unroll
      for (int r = 0; r < 16; ++r) {
        const int kg = k * 32 + (r & 3) + 8 * (r >> 2) + 4 * h;
        if (kg > qg) sv[r] = -1e30f;
      }
    }

    // p = exp2(s), pack (truncate) via v_perm
    u32 pk[8];
    #pragma unroll
    for (int g2 = 0; g2 < 4; ++g2) {
      const u32 u0 = __float_as_uint(__builtin_amdgcn_exp2f(sv[4 * g2 + 0]));
      const u32 u1 = __float_as_uint(__builtin_amdgcn_exp2f(sv[4 * g2 + 1]));
      const u32 u2 = __float_as_uint(__builtin_amdgcn_exp2f(sv[4 * g2 + 2]));
      const u32 u3 = __float_as_uint(__builtin_amdgcn_exp2f(sv[4 * g2 + 3]));
      pk[2 * g2]     = __builtin_amdgcn_perm(u1, u0, 0x07060302u);
      pk[2 * g2 + 1] = __builtin_amdgcn_perm(u3, u2, 0x07060302u);
    }

    // exchange partner half via permlane32_swap; PV + ones-MFMA for l
    {
      union { u32 u[4]; short8 s8; } pf;
      swap32(pk[0], pk[2], pf.u[0], pf.u[2]);
      swap32(pk[1], pk[3], pf.u[1], pf.u[3]);
      __builtin_amdgcn_s_setprio(1);
      acc0 = __builtin_amdgcn_mfma_f32_32x32x16_bf16(pf.s8, vc[0], acc0, 0, 0, 0);
      acc1 = __builtin_amdgcn_mfma_f32_32x32x16_bf16(pf.s8, vc[1], acc1, 0, 0, 0);
      lacc = __builtin_amdgcn_mfma_f32_32x32x16_bf16(pf.s8, ones,  lacc, 0, 0, 0);
      __builtin_amdgcn_s_setprio(0);
    }
    {
      union { u32 u[4]; short8 s8; } pf;
      swap32(pk[4], pk[6], pf.u[0], pf.u[2]);
      swap32(pk[5], pk[7], pf.u[1], pf.u[3]);
      __builtin_amdgcn_s_setprio(1);
      acc0 = __builtin_amdgcn_mfma_f32_32x32x16_bf16(pf.s8, vc[2], acc0, 0, 0, 0);
      acc1 = __builtin_amdgcn_mfma_f32_32x32x16_bf16(pf.s8, vc[3], acc1, 0, 0, 0);
      lacc = __builtin_amdgcn_mfma_f32_32x32x16_bf16(pf.s8, ones,  lacc, 0, 0, 0);
      __builtin_amdgcn_s_setprio(0);
    }
  };

  int k = 0;
  while (true) {
    step(kA, vA, kB, vB, k); if (++k > s) break;
    step(kB, vB, kA, vA, k); if (++k > s) break;
  }

  // ---- wave-local epilogue: O = acc / l, final fp32 ----
  #pragma unroll
  for (int r = 0; r < 16; ++r) {
    const int row = (r & 3) + 8 * (r >> 2) + 4 * h;
    const float inv = 1.f / lacc[r];
    float* op = O + ((size_t)bh * kS + q0 + row) * kD;
    op[l31]      = acc0[r] * inv;
    op[l31 + 32] = acc1[r] * inv;
  }
}

extern "C" void kernel_launch(void* const* d_in, const int* in_sizes, int n_in,
                              void* d_out, int out_size, void* d_ws, size_t ws_size,
                              hipStream_t stream) {
  const float* Q = (const float*)d_in[0];
  const float* K = (const float*)d_in[1];
  const float* V = (const float*)d_in[2];
  float* O = (float*)d_out;

  const size_t nKV = (size_t)kBH * kS * kD;      // 4.19M elems
  u16* Qf = (u16*)d_ws;                          // 8.39 MB
  u16* Kf = Qf + nKV;                            // 8.39 MB
  u16* Vf = Kf + nKV;                            // 8.39 MB

  dim3 gprep(kS / 64, kBH);
  prep_kernel<<<gprep, 256, 0, stream>>>(Q, K, V, Qf, Kf, Vf);
  fattn_kernel<<<2048, 64, 0, stream>>>(Qf, Kf, Vf, O);
}